// Round 9
// baseline (485.650 us; speedup 1.0000x reference)
//
#include <hip/hip_runtime.h>
#include <hip/hip_bf16.h>

#define NNODES 100000
#define NEDGES 1600000
#define DF 128
#define NC 40
#define NCP 48          // padded fc cols (3 x 16)
#define NB 196          // CSR bins: dst>>9, 512 nodes/bin
#define CH 4096         // edges per binscatter/bincount block

typedef __bf16 bf16x8 __attribute__((ext_vector_type(8)));
typedef float f32x4 __attribute__((ext_vector_type(4)));

__device__ __forceinline__ unsigned short f2bf(float f) {
    unsigned int u = __builtin_bit_cast(unsigned int, f);
    u = (u + 0x7FFFu + ((u >> 16) & 1u)) >> 16;   // RNE
    return (unsigned short)u;
}
__device__ __forceinline__ float bf2f(unsigned short s) {
    unsigned int u = ((unsigned int)s) << 16;
    return __builtin_bit_cast(float, u);
}
__device__ __forceinline__ float bfLo(unsigned int u) {
    return __builtin_bit_cast(float, u << 16);
}
__device__ __forceinline__ float bfHi(unsigned int u) {
    return __builtin_bit_cast(float, u & 0xFFFF0000u);
}

// ---------------- dtype detection (flags[0]: ei is int64; flags[1]: floats are bf16)
__global__ void k_detect(const unsigned int* __restrict__ ei32,
                         const unsigned int* __restrict__ x32,
                         int* __restrict__ flags) {
    __shared__ unsigned int rOr[256];
    __shared__ int rCnt[256];
    unsigned int o = 0; int c = 0;
    for (int i = threadIdx.x; i < 1024; i += 256) o |= ei32[2 * i + 1];
    for (int i = threadIdx.x; i < 4096; i += 256) {
        unsigned int e = (x32[i] >> 7) & 0xFFu;
        c += (e >= 100u && e <= 140u) ? 1 : 0;
    }
    rOr[threadIdx.x] = o; rCnt[threadIdx.x] = c;
    __syncthreads();
    for (int s = 128; s; s >>= 1) {
        if ((int)threadIdx.x < s) {
            rOr[threadIdx.x] |= rOr[threadIdx.x + s];
            rCnt[threadIdx.x] += rCnt[threadIdx.x + s];
        }
        __syncthreads();
    }
    if (threadIdx.x == 0) {
        flags[0] = (rOr[0] == 0u) ? 1 : 0;
        flags[1] = (rCnt[0] > 2457) ? 1 : 0;
    }
}

__device__ __forceinline__ int ldIdx(const void* ei, int flag64, int i) {
    return flag64 ? (int)((const long long*)ei)[i] : ((const int*)ei)[i];
}

// ---------------- features -> canonical bf16
__global__ __launch_bounds__(256) void k_cvt_feat(const void* __restrict__ src,
                                                  const int* __restrict__ flags,
                                                  unsigned short* __restrict__ dst, int n) {
    int i = blockIdx.x * 256 + threadIdx.x;
    if (i >= n) return;
    dst[i] = flags[1] ? ((const unsigned short*)src)[i]
                      : f2bf(((const float*)src)[i]);
}

// ---------------- all weights (transposed bf16) + biases (fp32) in ONE launch.
__global__ __launch_bounds__(256) void k_wprep(const void* w1a, const void* w1b,
                                               const void* w2a, const void* w2b,
                                               const void* wfc,
                                               const void* b1a, const void* b1b,
                                               const void* b2a, const void* b2b,
                                               const void* bfc,
                                               const int* __restrict__ flags,
                                               unsigned short* __restrict__ wAll,
                                               float* __restrict__ bAll) {
    int idx = blockIdx.x * 256 + threadIdx.x;
    int bf = flags[1];
    auto ldf = [&](const void* p, int i) -> float {
        return bf ? bf2f(((const unsigned short*)p)[i]) : ((const float*)p)[i];
    };
    if (idx < 65536) {                       // 4 square transposes
        int wi = idx >> 14, r = idx & 16383;
        int n = r >> 7, k = r & 127;
        const void* s = (wi == 0) ? w1a : (wi == 1) ? w1b : (wi == 2) ? w2a : w2b;
        wAll[idx] = f2bf(ldf(s, k * 128 + n));
    } else if (idx < 65536 + NCP * 128) {    // wfc transpose, zero pad
        int r = idx - 65536;
        int n = r >> 7, k = r & 127;
        wAll[idx] = (n < NC) ? f2bf(ldf(wfc, k * NC + n)) : (unsigned short)0;
    } else if (idx < 65536 + NCP * 128 + 512 + NC) {
        int r = idx - (65536 + NCP * 128);
        const void* s; int i;
        if (r < 128)      { s = b1a; i = r; }
        else if (r < 256) { s = b1b; i = r - 128; }
        else if (r < 384) { s = b2a; i = r - 256; }
        else if (r < 512) { s = b2b; i = r - 384; }
        else              { s = bfc; i = r - 512; }
        bAll[r] = ldf(s, i);
    }
}

// ================= binned CSR build =================
__global__ __launch_bounds__(256) void k_bincount(const void* __restrict__ ei,
                                                  const int* __restrict__ flags,
                                                  int* __restrict__ binCnt) {
    __shared__ int l[NB];
    int t = threadIdx.x;
    int f64 = flags[0];
    for (int i = t; i < NB; i += 256) l[i] = 0;
    __syncthreads();
    int base = blockIdx.x * CH;
#pragma unroll
    for (int k = 0; k < CH / 256; k++) {
        int e = base + k * 256 + t;
        if (e < NEDGES) atomicAdd(&l[ldIdx(ei, f64, NEDGES + e) >> 9], 1);
    }
    __syncthreads();
    for (int i = t; i < NB; i += 256)
        if (l[i]) atomicAdd(&binCnt[i], l[i]);
}

__global__ __launch_bounds__(256) void k_binscan(const int* __restrict__ binCnt,
                                                 int* __restrict__ binOfs,
                                                 int* __restrict__ binCur) {
    __shared__ int sh[256];
    int t = threadIdx.x;
    int v = (t < NB) ? binCnt[t] : 0;
    sh[t] = v;
    __syncthreads();
    for (int off = 1; off < 256; off <<= 1) {
        int x = (t >= off) ? sh[t - off] : 0;
        __syncthreads();
        sh[t] += x;
        __syncthreads();
    }
    if (t < NB) {
        binOfs[t + 1] = sh[t];
        binCur[t] = sh[t] - v;      // exclusive
    }
    if (t == 0) binOfs[0] = 0;
}

__global__ __launch_bounds__(256) void k_binscatter(const void* __restrict__ ei,
                                                    const int* __restrict__ flags,
                                                    int* __restrict__ binCur,
                                                    int2* __restrict__ ebin) {
    __shared__ int lcnt[NB], lbase[NB], lofs[NB];
    int t = threadIdx.x;
    int f64 = flags[0];
    for (int i = t; i < NB; i += 256) lcnt[i] = 0;
    __syncthreads();
    int base = blockIdx.x * CH;
    int2 ed[CH / 256];
    int bn[CH / 256];
#pragma unroll
    for (int k = 0; k < CH / 256; k++) {
        int e = base + k * 256 + t;
        if (e < NEDGES) {
            ed[k].x = ldIdx(ei, f64, e);
            ed[k].y = ldIdx(ei, f64, NEDGES + e);
            bn[k] = ed[k].y >> 9;
            atomicAdd(&lcnt[bn[k]], 1);
        } else bn[k] = -1;
    }
    __syncthreads();
    if (t < NB) {
        int c = lcnt[t];
        lbase[t] = c ? atomicAdd(&binCur[t], c) : 0;
        lofs[t] = 0;
    }
    __syncthreads();
#pragma unroll
    for (int k = 0; k < CH / 256; k++) {
        if (bn[k] >= 0) {
            int p = lbase[bn[k]] + atomicAdd(&lofs[bn[k]], 1);
            ebin[p] = ed[k];
        }
    }
}

__global__ __launch_bounds__(256) void k_binfill(const int2* __restrict__ ebin,
                                                 const int* __restrict__ binOfs,
                                                 int* __restrict__ rowptr,
                                                 int* __restrict__ perm) {
    __shared__ int deg[512], lptr[512], ssum[256];
    int b = blockIdx.x, t = threadIdx.x;
    int n0 = b << 9;
    int nn = NNODES - n0; if (nn > 512) nn = 512;
    int e0 = binOfs[b], e1 = binOfs[b + 1];
    deg[t] = 0; deg[t + 256] = 0;
    __syncthreads();
    for (int e = e0 + t; e < e1; e += 256)
        atomicAdd(&deg[ebin[e].y - n0], 1);
    __syncthreads();
    int d0 = deg[2 * t], d1 = deg[2 * t + 1];
    int s = d0 + d1;
    ssum[t] = s;
    __syncthreads();
    for (int off = 1; off < 256; off <<= 1) {
        int x = (t >= off) ? ssum[t - off] : 0;
        __syncthreads();
        ssum[t] += x;
        __syncthreads();
    }
    int ex = ssum[t] - s;
    lptr[2 * t] = ex;
    lptr[2 * t + 1] = ex + d0;
    if (2 * t < nn)     rowptr[n0 + 2 * t] = e0 + ex;
    if (2 * t + 1 < nn) rowptr[n0 + 2 * t + 1] = e0 + ex + d0;
    if (b == NB - 1 && t == 0) rowptr[NNODES] = e1;
    deg[2 * t] = 0; deg[2 * t + 1] = 0;   // reuse as cursor
    __syncthreads();
    for (int e = e0 + t; e < e1; e += 256) {
        int2 ed = ebin[e];
        int d = ed.y - n0;
        int pos = e0 + lptr[d] + atomicAdd(&deg[d], 1);
        perm[pos] = ed.x;
    }
}

// ================= gather aggregation =================
__global__ __launch_bounds__(256) void k_gather(const unsigned short* __restrict__ feat,
                                                const unsigned short* __restrict__ x,
                                                const int* __restrict__ rowptr,
                                                const int* __restrict__ perm,
                                                unsigned short* __restrict__ out) {
    int wave = threadIdx.x >> 6, lane = threadIdx.x & 63;
    int i = blockIdx.x * 4 + wave;        // NNODES = 25000*4 exactly
    const unsigned int* F = (const unsigned int*)feat;
    unsigned int xv = ((const unsigned int*)x)[i * 64 + lane];
    float accL = bfLo(xv);
    float accH = bfHi(xv);
    int jb = rowptr[i], je = rowptr[i + 1];
    int j = jb;
    for (; j + 8 <= je; j += 8) {
        int s[8];
#pragma unroll
        for (int k = 0; k < 8; k++) s[k] = perm[j + k];
        unsigned int v[8];
#pragma unroll
        for (int k = 0; k < 8; k++) v[k] = F[s[k] * 64 + lane];
#pragma unroll
        for (int k = 0; k < 8; k++) {
            accL += bfLo(v[k]);
            accH += bfHi(v[k]);
        }
    }
    for (; j < je; j++) {
        unsigned int v = F[perm[j] * 64 + lane];
        accL += bfLo(v);
        accH += bfHi(v);
    }
    unsigned int r = ((unsigned int)f2bf(accH) << 16) | f2bf(accL);
    ((unsigned int*)out)[i * 64 + lane] = r;
}

// ---------------- register-resident-B GEMM: C = relu(A @ W + bias), bf16.
// Wave holds ALL of W as 32 bf16x8 fragments (128 VGPR) -> no B re-reads,
// per tile only 4 A-loads + 32 MFMA + stores. HBM-bound by design.
// Layouts (m89/m91): A[m=lane&15][k=quad*8+j]; B[k=quad*8+j][n=lane&15];
// D: col=lane&15, row=quad*4+reg.
__global__ __launch_bounds__(256, 2) void k_gemm_rb(const unsigned short* __restrict__ A,
                                                    const unsigned short* __restrict__ WT,
                                                    const float* __restrict__ bias,
                                                    unsigned short* __restrict__ out) {
    int wave = threadIdx.x >> 6, lane = threadIdx.x & 63;
    int m = lane & 15, quad = lane >> 4;
    int tile = blockIdx.x * 4 + wave;
    if (tile >= NNODES / 16) return;
    int r0 = tile * 16;

    bf16x8 bfr[8][4];
#pragma unroll
    for (int nt = 0; nt < 8; nt++) {
        const unsigned short* Bb = WT + (nt * 16 + m) * DF + quad * 8;
#pragma unroll
        for (int ks = 0; ks < 4; ks++)
            bfr[nt][ks] = *(const bf16x8*)(Bb + ks * 32);
    }

    const unsigned short* Ab = A + (r0 + m) * DF + quad * 8;
    bf16x8 a[4];
#pragma unroll
    for (int ks = 0; ks < 4; ks++) a[ks] = *(const bf16x8*)(Ab + ks * 32);

    f32x4 acc[8];
#pragma unroll
    for (int nt = 0; nt < 8; nt++) acc[nt] = (f32x4){0.f, 0.f, 0.f, 0.f};
#pragma unroll
    for (int nt = 0; nt < 8; nt++)
#pragma unroll
        for (int ks = 0; ks < 4; ks++)
            acc[nt] = __builtin_amdgcn_mfma_f32_16x16x32_bf16(a[ks], bfr[nt][ks], acc[nt], 0, 0, 0);

#pragma unroll
    for (int nt = 0; nt < 8; nt++) {
        int col = nt * 16 + m;
        float bv = bias[col];
#pragma unroll
        for (int reg = 0; reg < 4; reg++) {
            int row = r0 + quad * 4 + reg;
            float v = acc[nt][reg] + bv;
            if (v < 0.f) v = 0.f;
            out[row * DF + col] = f2bf(v);
        }
    }
}

// ---------------- fc (128 -> 40, padded 48) reg-B GEMM + fused log_softmax.
__global__ __launch_bounds__(256, 2) void k_fc_rb(const unsigned short* __restrict__ A,
                                                  const unsigned short* __restrict__ WfcT,
                                                  const float* __restrict__ bfc,
                                                  const int* __restrict__ flags,
                                                  void* __restrict__ out) {
    int wave = threadIdx.x >> 6, lane = threadIdx.x & 63;
    int m = lane & 15, quad = lane >> 4;
    int tile = blockIdx.x * 4 + wave;
    if (tile >= NNODES / 16) return;
    int r0 = tile * 16;
    bool valid2 = (m < 8);
    int obf = flags[1];

    bf16x8 bfr[3][4];
#pragma unroll
    for (int nt = 0; nt < 3; nt++) {
        const unsigned short* Bb = WfcT + (nt * 16 + m) * DF + quad * 8;
#pragma unroll
        for (int ks = 0; ks < 4; ks++)
            bfr[nt][ks] = *(const bf16x8*)(Bb + ks * 32);
    }

    const unsigned short* Ab = A + (r0 + m) * DF + quad * 8;
    bf16x8 a[4];
#pragma unroll
    for (int ks = 0; ks < 4; ks++) a[ks] = *(const bf16x8*)(Ab + ks * 32);

    f32x4 acc[3];
#pragma unroll
    for (int nt = 0; nt < 3; nt++) acc[nt] = (f32x4){0.f, 0.f, 0.f, 0.f};
#pragma unroll
    for (int nt = 0; nt < 3; nt++)
#pragma unroll
        for (int ks = 0; ks < 4; ks++)
            acc[nt] = __builtin_amdgcn_mfma_f32_16x16x32_bf16(a[ks], bfr[nt][ks], acc[nt], 0, 0, 0);

    float bv0 = bfc[m], bv1 = bfc[16 + m];
    float bv2 = valid2 ? bfc[32 + m] : 0.f;
#pragma unroll
    for (int reg = 0; reg < 4; reg++) {
        float v0 = acc[0][reg] + bv0;
        float v1 = acc[1][reg] + bv1;
        float v2 = valid2 ? (acc[2][reg] + bv2) : -3.0e38f;
        float mx = fmaxf(fmaxf(v0, v1), v2);
#pragma unroll
        for (int off = 1; off < 16; off <<= 1) mx = fmaxf(mx, __shfl_xor(mx, off, 16));
        float e = __expf(v0 - mx) + __expf(v1 - mx) + (valid2 ? __expf(v2 - mx) : 0.f);
#pragma unroll
        for (int off = 1; off < 16; off <<= 1) e += __shfl_xor(e, off, 16);
        float l = mx + __logf(e);
        int row = r0 + quad * 4 + reg;
        if (obf) {
            unsigned short* o = (unsigned short*)out + row * NC;
            o[m] = f2bf(v0 - l);
            o[16 + m] = f2bf(v1 - l);
            if (valid2) o[32 + m] = f2bf(v2 - l);
        } else {
            float* o = (float*)out + row * NC;
            o[m] = v0 - l;
            o[16 + m] = v1 - l;
            if (valid2) o[32 + m] = v2 - l;
        }
    }
}

extern "C" void kernel_launch(void* const* d_in, const int* in_sizes, int n_in,
                              void* d_out, int out_size, void* d_ws, size_t ws_size,
                              hipStream_t stream) {
    const void* x   = d_in[0];
    const void* ei  = d_in[1];
    const void* w1a = d_in[2];
    const void* b1a = d_in[3];
    const void* w1b = d_in[4];
    const void* b1b = d_in[5];
    const void* w2a = d_in[6];
    const void* b2a = d_in[7];
    const void* w2b = d_in[8];
    const void* b2b = d_in[9];
    const void* wfc = d_in[10];
    const void* bfc = d_in[11];

    char* ws = (char*)d_ws;
    size_t off = 0;
    auto alloc = [&](size_t bytes) {
        void* p = ws + off;
        off += (bytes + 255) & ~(size_t)255;
        return p;
    };
    unsigned short* B0    = (unsigned short*)alloc((size_t)NNODES * DF * 2);
    unsigned short* B1    = (unsigned short*)alloc((size_t)NNODES * DF * 2);
    unsigned short* B2    = (unsigned short*)alloc((size_t)NNODES * DF * 2);
    int2*           ebin  = (int2*)alloc((size_t)NEDGES * 8);
    int*            perm  = (int*)alloc((size_t)NEDGES * 4);
    int*            rowptr= (int*)alloc((size_t)(NNODES + 1) * 4);
    int*            binCnt= (int*)alloc(NB * 4);
    int*            binOfs= (int*)alloc((NB + 1) * 4);
    int*            binCur= (int*)alloc(NB * 4);
    int*            flags = (int*)alloc(256);
    unsigned short* wAll  = (unsigned short*)alloc((4 * 16384 + NCP * 128) * 2);
    float*          bAll  = (float*)alloc((512 + NC) * 4);

    unsigned short* w1aT = wAll;
    unsigned short* w1bT = wAll + 16384;
    unsigned short* w2aT = wAll + 32768;
    unsigned short* w2bT = wAll + 49152;
    unsigned short* wfcT = wAll + 65536;
    float* b1af = bAll;
    float* b1bf = bAll + 128;
    float* b2af = bAll + 256;
    float* b2bf = bAll + 384;
    float* bfcf = bAll + 512;

    // ---- dtype detection + canonicalization
    k_detect<<<1, 256, 0, stream>>>((const unsigned int*)ei, (const unsigned int*)x, flags);
    k_cvt_feat<<<(NNODES * DF + 255) / 256, 256, 0, stream>>>(x, flags, B0, NNODES * DF);

    int wprepN = 4 * 16384 + NCP * 128 + 512 + NC;
    k_wprep<<<(wprepN + 255) / 256, 256, 0, stream>>>(w1a, w1b, w2a, w2b, wfc,
                                                      b1a, b1b, b2a, b2b, bfc,
                                                      flags, wAll, bAll);

    // ---- binned CSR build (reads edge_index directly)
    hipMemsetAsync(binCnt, 0, NB * 4, stream);
    int nEB = (NEDGES + CH - 1) / CH;                          // 391
    k_bincount<<<nEB, 256, 0, stream>>>(ei, flags, binCnt);
    k_binscan<<<1, 256, 0, stream>>>(binCnt, binOfs, binCur);
    k_binscatter<<<nEB, 256, 0, stream>>>(ei, flags, binCur, ebin);
    k_binfill<<<NB, 256, 0, stream>>>(ebin, binOfs, rowptr, perm);

    const int gemmGrid = (NNODES / 16 + 3) / 4;                // 1563
    const int gatherGrid = NNODES / 4;                         // 25000

    // ---- layer 1
    k_gather<<<gatherGrid, 256, 0, stream>>>(B0, B0, rowptr, perm, B1);
    k_gemm_rb<<<gemmGrid, 256, 0, stream>>>(B1, w1aT, b1af, B2);
    k_gemm_rb<<<gemmGrid, 256, 0, stream>>>(B2, w1bT, b1bf, B1);   // h1 -> B1

    // ---- layer 2
    k_gather<<<gatherGrid, 256, 0, stream>>>(B1, B1, rowptr, perm, B2);
    k_gemm_rb<<<gemmGrid, 256, 0, stream>>>(B2, w2aT, b2af, B0);
    k_gemm_rb<<<gemmGrid, 256, 0, stream>>>(B0, w2bT, b2bf, B2);   // h2 -> B2

    // ---- fc + log_softmax
    k_fc_rb<<<gemmGrid, 256, 0, stream>>>(B2, wfcT, bfcf, flags, d_out);
}

// Round 10
// 417.242 us; speedup vs baseline: 1.1640x; 1.1640x over previous
//
#include <hip/hip_runtime.h>
#include <hip/hip_bf16.h>

#define NNODES 100000
#define NEDGES 1600000
#define DF 128
#define NC 40
#define NCP 48          // padded fc cols (3 x 16)
#define NB 196          // CSR bins: dst>>9, 512 nodes/bin
#define CH 4096         // edges per binscatter/bincount block
#define GEMM_BLOCKS 512 // persistent: 2 blocks/CU x 256 CU
#define GEMM_WAVES (GEMM_BLOCKS * 4)

typedef __bf16 bf16x8 __attribute__((ext_vector_type(8)));
typedef float f32x4 __attribute__((ext_vector_type(4)));

__device__ __forceinline__ unsigned short f2bf(float f) {
    unsigned int u = __builtin_bit_cast(unsigned int, f);
    u = (u + 0x7FFFu + ((u >> 16) & 1u)) >> 16;   // RNE
    return (unsigned short)u;
}
__device__ __forceinline__ float bf2f(unsigned short s) {
    unsigned int u = ((unsigned int)s) << 16;
    return __builtin_bit_cast(float, u);
}
__device__ __forceinline__ float bfLo(unsigned int u) {
    return __builtin_bit_cast(float, u << 16);
}
__device__ __forceinline__ float bfHi(unsigned int u) {
    return __builtin_bit_cast(float, u & 0xFFFF0000u);
}

// ---------------- dtype detection (flags[0]: ei is int64; flags[1]: floats are bf16)
__global__ void k_detect(const unsigned int* __restrict__ ei32,
                         const unsigned int* __restrict__ x32,
                         int* __restrict__ flags) {
    __shared__ unsigned int rOr[256];
    __shared__ int rCnt[256];
    unsigned int o = 0; int c = 0;
    for (int i = threadIdx.x; i < 1024; i += 256) o |= ei32[2 * i + 1];
    for (int i = threadIdx.x; i < 4096; i += 256) {
        unsigned int e = (x32[i] >> 7) & 0xFFu;
        c += (e >= 100u && e <= 140u) ? 1 : 0;
    }
    rOr[threadIdx.x] = o; rCnt[threadIdx.x] = c;
    __syncthreads();
    for (int s = 128; s; s >>= 1) {
        if ((int)threadIdx.x < s) {
            rOr[threadIdx.x] |= rOr[threadIdx.x + s];
            rCnt[threadIdx.x] += rCnt[threadIdx.x + s];
        }
        __syncthreads();
    }
    if (threadIdx.x == 0) {
        flags[0] = (rOr[0] == 0u) ? 1 : 0;
        flags[1] = (rCnt[0] > 2457) ? 1 : 0;
    }
}

__device__ __forceinline__ int ldIdx(const void* ei, int flag64, int i) {
    return flag64 ? (int)((const long long*)ei)[i] : ((const int*)ei)[i];
}

// ---------------- features -> canonical bf16
__global__ __launch_bounds__(256) void k_cvt_feat(const void* __restrict__ src,
                                                  const int* __restrict__ flags,
                                                  unsigned short* __restrict__ dst, int n) {
    int i = blockIdx.x * 256 + threadIdx.x;
    if (i >= n) return;
    dst[i] = flags[1] ? ((const unsigned short*)src)[i]
                      : f2bf(((const float*)src)[i]);
}

// ---------------- all weights (transposed bf16) + biases (fp32) in ONE launch.
__global__ __launch_bounds__(256) void k_wprep(const void* w1a, const void* w1b,
                                               const void* w2a, const void* w2b,
                                               const void* wfc,
                                               const void* b1a, const void* b1b,
                                               const void* b2a, const void* b2b,
                                               const void* bfc,
                                               const int* __restrict__ flags,
                                               unsigned short* __restrict__ wAll,
                                               float* __restrict__ bAll) {
    int idx = blockIdx.x * 256 + threadIdx.x;
    int bf = flags[1];
    auto ldf = [&](const void* p, int i) -> float {
        return bf ? bf2f(((const unsigned short*)p)[i]) : ((const float*)p)[i];
    };
    if (idx < 65536) {                       // 4 square transposes
        int wi = idx >> 14, r = idx & 16383;
        int n = r >> 7, k = r & 127;
        const void* s = (wi == 0) ? w1a : (wi == 1) ? w1b : (wi == 2) ? w2a : w2b;
        wAll[idx] = f2bf(ldf(s, k * 128 + n));
    } else if (idx < 65536 + NCP * 128) {    // wfc transpose, zero pad
        int r = idx - 65536;
        int n = r >> 7, k = r & 127;
        wAll[idx] = (n < NC) ? f2bf(ldf(wfc, k * NC + n)) : (unsigned short)0;
    } else if (idx < 65536 + NCP * 128 + 512 + NC) {
        int r = idx - (65536 + NCP * 128);
        const void* s; int i;
        if (r < 128)      { s = b1a; i = r; }
        else if (r < 256) { s = b1b; i = r - 128; }
        else if (r < 384) { s = b2a; i = r - 256; }
        else if (r < 512) { s = b2b; i = r - 384; }
        else              { s = bfc; i = r - 512; }
        bAll[r] = ldf(s, i);
    }
}

// ================= binned CSR build =================
__global__ __launch_bounds__(256) void k_bincount(const void* __restrict__ ei,
                                                  const int* __restrict__ flags,
                                                  int* __restrict__ binCnt) {
    __shared__ int l[NB];
    int t = threadIdx.x;
    int f64 = flags[0];
    for (int i = t; i < NB; i += 256) l[i] = 0;
    __syncthreads();
    int base = blockIdx.x * CH;
#pragma unroll
    for (int k = 0; k < CH / 256; k++) {
        int e = base + k * 256 + t;
        if (e < NEDGES) atomicAdd(&l[ldIdx(ei, f64, NEDGES + e) >> 9], 1);
    }
    __syncthreads();
    for (int i = t; i < NB; i += 256)
        if (l[i]) atomicAdd(&binCnt[i], l[i]);
}

__global__ __launch_bounds__(256) void k_binscan(const int* __restrict__ binCnt,
                                                 int* __restrict__ binOfs,
                                                 int* __restrict__ binCur) {
    __shared__ int sh[256];
    int t = threadIdx.x;
    int v = (t < NB) ? binCnt[t] : 0;
    sh[t] = v;
    __syncthreads();
    for (int off = 1; off < 256; off <<= 1) {
        int x = (t >= off) ? sh[t - off] : 0;
        __syncthreads();
        sh[t] += x;
        __syncthreads();
    }
    if (t < NB) {
        binOfs[t + 1] = sh[t];
        binCur[t] = sh[t] - v;      // exclusive
    }
    if (t == 0) binOfs[0] = 0;
}

__global__ __launch_bounds__(256) void k_binscatter(const void* __restrict__ ei,
                                                    const int* __restrict__ flags,
                                                    int* __restrict__ binCur,
                                                    int2* __restrict__ ebin) {
    __shared__ int lcnt[NB], lbase[NB], lofs[NB];
    int t = threadIdx.x;
    int f64 = flags[0];
    for (int i = t; i < NB; i += 256) lcnt[i] = 0;
    __syncthreads();
    int base = blockIdx.x * CH;
    int2 ed[CH / 256];
    int bn[CH / 256];
#pragma unroll
    for (int k = 0; k < CH / 256; k++) {
        int e = base + k * 256 + t;
        if (e < NEDGES) {
            ed[k].x = ldIdx(ei, f64, e);
            ed[k].y = ldIdx(ei, f64, NEDGES + e);
            bn[k] = ed[k].y >> 9;
            atomicAdd(&lcnt[bn[k]], 1);
        } else bn[k] = -1;
    }
    __syncthreads();
    if (t < NB) {
        int c = lcnt[t];
        lbase[t] = c ? atomicAdd(&binCur[t], c) : 0;
        lofs[t] = 0;
    }
    __syncthreads();
#pragma unroll
    for (int k = 0; k < CH / 256; k++) {
        if (bn[k] >= 0) {
            int p = lbase[bn[k]] + atomicAdd(&lofs[bn[k]], 1);
            ebin[p] = ed[k];
        }
    }
}

__global__ __launch_bounds__(256) void k_binfill(const int2* __restrict__ ebin,
                                                 const int* __restrict__ binOfs,
                                                 int* __restrict__ rowptr,
                                                 int* __restrict__ perm) {
    __shared__ int deg[512], lptr[512], ssum[256];
    int b = blockIdx.x, t = threadIdx.x;
    int n0 = b << 9;
    int nn = NNODES - n0; if (nn > 512) nn = 512;
    int e0 = binOfs[b], e1 = binOfs[b + 1];
    deg[t] = 0; deg[t + 256] = 0;
    __syncthreads();
    for (int e = e0 + t; e < e1; e += 256)
        atomicAdd(&deg[ebin[e].y - n0], 1);
    __syncthreads();
    int d0 = deg[2 * t], d1 = deg[2 * t + 1];
    int s = d0 + d1;
    ssum[t] = s;
    __syncthreads();
    for (int off = 1; off < 256; off <<= 1) {
        int x = (t >= off) ? ssum[t - off] : 0;
        __syncthreads();
        ssum[t] += x;
        __syncthreads();
    }
    int ex = ssum[t] - s;
    lptr[2 * t] = ex;
    lptr[2 * t + 1] = ex + d0;
    if (2 * t < nn)     rowptr[n0 + 2 * t] = e0 + ex;
    if (2 * t + 1 < nn) rowptr[n0 + 2 * t + 1] = e0 + ex + d0;
    if (b == NB - 1 && t == 0) rowptr[NNODES] = e1;
    deg[2 * t] = 0; deg[2 * t + 1] = 0;   // reuse as cursor
    __syncthreads();
    for (int e = e0 + t; e < e1; e += 256) {
        int2 ed = ebin[e];
        int d = ed.y - n0;
        int pos = e0 + lptr[d] + atomicAdd(&deg[d], 1);
        perm[pos] = ed.x;
    }
}

// ================= gather aggregation =================
__global__ __launch_bounds__(256) void k_gather(const unsigned short* __restrict__ feat,
                                                const unsigned short* __restrict__ x,
                                                const int* __restrict__ rowptr,
                                                const int* __restrict__ perm,
                                                unsigned short* __restrict__ out) {
    int wave = threadIdx.x >> 6, lane = threadIdx.x & 63;
    int i = blockIdx.x * 4 + wave;        // NNODES = 25000*4 exactly
    const unsigned int* F = (const unsigned int*)feat;
    unsigned int xv = ((const unsigned int*)x)[i * 64 + lane];
    float accL = bfLo(xv);
    float accH = bfHi(xv);
    int jb = rowptr[i], je = rowptr[i + 1];
    int j = jb;
    for (; j + 8 <= je; j += 8) {
        int s[8];
#pragma unroll
        for (int k = 0; k < 8; k++) s[k] = perm[j + k];
        unsigned int v[8];
#pragma unroll
        for (int k = 0; k < 8; k++) v[k] = F[s[k] * 64 + lane];
#pragma unroll
        for (int k = 0; k < 8; k++) {
            accL += bfLo(v[k]);
            accH += bfHi(v[k]);
        }
    }
    for (; j < je; j++) {
        unsigned int v = F[perm[j] * 64 + lane];
        accL += bfLo(v);
        accH += bfHi(v);
    }
    unsigned int r = ((unsigned int)f2bf(accH) << 16) | f2bf(accL);
    ((unsigned int*)out)[i * 64 + lane] = r;
}

// ---------------- persistent register-resident-B GEMM: C = relu(A@W + bias).
// 2048 waves grid-stride 6250 row-tiles (~3 each). W (128 VGPR) + bias loaded
// ONCE per wave; per tile: 4 A-loads (b128) + 32 MFMA + stores. Independent
// iterations let the compiler pipeline next-tile A-loads under MFMAs.
// Layouts (m89/m91): A[m=lane&15][k=quad*8+j]; B[k=quad*8+j][n=lane&15];
// D: col=lane&15, row=quad*4+reg.
__global__ __launch_bounds__(256, 2) void k_gemm_rb(const unsigned short* __restrict__ A,
                                                    const unsigned short* __restrict__ WT,
                                                    const float* __restrict__ bias,
                                                    unsigned short* __restrict__ out) {
    int gw = blockIdx.x * 4 + (threadIdx.x >> 6);   // global wave id
    int lane = threadIdx.x & 63;
    int m = lane & 15, quad = lane >> 4;

    bf16x8 bfr[8][4];
#pragma unroll
    for (int nt = 0; nt < 8; nt++) {
        const unsigned short* Bb = WT + (nt * 16 + m) * DF + quad * 8;
#pragma unroll
        for (int ks = 0; ks < 4; ks++)
            bfr[nt][ks] = *(const bf16x8*)(Bb + ks * 32);
    }
    float bv[8];
#pragma unroll
    for (int nt = 0; nt < 8; nt++) bv[nt] = bias[nt * 16 + m];

    for (int tile = gw; tile < NNODES / 16; tile += GEMM_WAVES) {
        int r0 = tile * 16;
        const unsigned short* Ab = A + (r0 + m) * DF + quad * 8;
        bf16x8 a[4];
#pragma unroll
        for (int ks = 0; ks < 4; ks++) a[ks] = *(const bf16x8*)(Ab + ks * 32);

        f32x4 acc[8];
#pragma unroll
        for (int nt = 0; nt < 8; nt++) acc[nt] = (f32x4){0.f, 0.f, 0.f, 0.f};
#pragma unroll
        for (int nt = 0; nt < 8; nt++)
#pragma unroll
            for (int ks = 0; ks < 4; ks++)
                acc[nt] = __builtin_amdgcn_mfma_f32_16x16x32_bf16(a[ks], bfr[nt][ks], acc[nt], 0, 0, 0);

#pragma unroll
        for (int nt = 0; nt < 8; nt++) {
            int col = nt * 16 + m;
#pragma unroll
            for (int reg = 0; reg < 4; reg++) {
                int row = r0 + quad * 4 + reg;
                float v = acc[nt][reg] + bv[nt];
                if (v < 0.f) v = 0.f;
                out[row * DF + col] = f2bf(v);
            }
        }
    }
}

// ---------------- persistent fc (128 -> 40, padded 48) + fused log_softmax.
__global__ __launch_bounds__(256, 2) void k_fc_rb(const unsigned short* __restrict__ A,
                                                  const unsigned short* __restrict__ WfcT,
                                                  const float* __restrict__ bfc,
                                                  const int* __restrict__ flags,
                                                  void* __restrict__ out) {
    int gw = blockIdx.x * 4 + (threadIdx.x >> 6);
    int lane = threadIdx.x & 63;
    int m = lane & 15, quad = lane >> 4;
    bool valid2 = (m < 8);
    int obf = flags[1];

    bf16x8 bfr[3][4];
#pragma unroll
    for (int nt = 0; nt < 3; nt++) {
        const unsigned short* Bb = WfcT + (nt * 16 + m) * DF + quad * 8;
#pragma unroll
        for (int ks = 0; ks < 4; ks++)
            bfr[nt][ks] = *(const bf16x8*)(Bb + ks * 32);
    }
    float bv0 = bfc[m], bv1 = bfc[16 + m];
    float bv2 = valid2 ? bfc[32 + m] : 0.f;

    for (int tile = gw; tile < NNODES / 16; tile += GEMM_WAVES) {
        int r0 = tile * 16;
        const unsigned short* Ab = A + (r0 + m) * DF + quad * 8;
        bf16x8 a[4];
#pragma unroll
        for (int ks = 0; ks < 4; ks++) a[ks] = *(const bf16x8*)(Ab + ks * 32);

        f32x4 acc[3];
#pragma unroll
        for (int nt = 0; nt < 3; nt++) acc[nt] = (f32x4){0.f, 0.f, 0.f, 0.f};
#pragma unroll
        for (int nt = 0; nt < 3; nt++)
#pragma unroll
            for (int ks = 0; ks < 4; ks++)
                acc[nt] = __builtin_amdgcn_mfma_f32_16x16x32_bf16(a[ks], bfr[nt][ks], acc[nt], 0, 0, 0);

#pragma unroll
        for (int reg = 0; reg < 4; reg++) {
            float v0 = acc[0][reg] + bv0;
            float v1 = acc[1][reg] + bv1;
            float v2 = valid2 ? (acc[2][reg] + bv2) : -3.0e38f;
            float mx = fmaxf(fmaxf(v0, v1), v2);
#pragma unroll
            for (int off = 1; off < 16; off <<= 1) mx = fmaxf(mx, __shfl_xor(mx, off, 16));
            float e = __expf(v0 - mx) + __expf(v1 - mx) + (valid2 ? __expf(v2 - mx) : 0.f);
#pragma unroll
            for (int off = 1; off < 16; off <<= 1) e += __shfl_xor(e, off, 16);
            float l = mx + __logf(e);
            int row = r0 + quad * 4 + reg;
            if (obf) {
                unsigned short* o = (unsigned short*)out + row * NC;
                o[m] = f2bf(v0 - l);
                o[16 + m] = f2bf(v1 - l);
                if (valid2) o[32 + m] = f2bf(v2 - l);
            } else {
                float* o = (float*)out + row * NC;
                o[m] = v0 - l;
                o[16 + m] = v1 - l;
                if (valid2) o[32 + m] = v2 - l;
            }
        }
    }
}

extern "C" void kernel_launch(void* const* d_in, const int* in_sizes, int n_in,
                              void* d_out, int out_size, void* d_ws, size_t ws_size,
                              hipStream_t stream) {
    const void* x   = d_in[0];
    const void* ei  = d_in[1];
    const void* w1a = d_in[2];
    const void* b1a = d_in[3];
    const void* w1b = d_in[4];
    const void* b1b = d_in[5];
    const void* w2a = d_in[6];
    const void* b2a = d_in[7];
    const void* w2b = d_in[8];
    const void* b2b = d_in[9];
    const void* wfc = d_in[10];
    const void* bfc = d_in[11];

    char* ws = (char*)d_ws;
    size_t off = 0;
    auto alloc = [&](size_t bytes) {
        void* p = ws + off;
        off += (bytes + 255) & ~(size_t)255;
        return p;
    };
    unsigned short* B0    = (unsigned short*)alloc((size_t)NNODES * DF * 2);
    unsigned short* B1    = (unsigned short*)alloc((size_t)NNODES * DF * 2);
    unsigned short* B2    = (unsigned short*)alloc((size_t)NNODES * DF * 2);
    int2*           ebin  = (int2*)alloc((size_t)NEDGES * 8);
    int*            perm  = (int*)alloc((size_t)NEDGES * 4);
    int*            rowptr= (int*)alloc((size_t)(NNODES + 1) * 4);
    int*            binCnt= (int*)alloc(NB * 4);
    int*            binOfs= (int*)alloc((NB + 1) * 4);
    int*            binCur= (int*)alloc(NB * 4);
    int*            flags = (int*)alloc(256);
    unsigned short* wAll  = (unsigned short*)alloc((4 * 16384 + NCP * 128) * 2);
    float*          bAll  = (float*)alloc((512 + NC) * 4);

    unsigned short* w1aT = wAll;
    unsigned short* w1bT = wAll + 16384;
    unsigned short* w2aT = wAll + 32768;
    unsigned short* w2bT = wAll + 49152;
    unsigned short* wfcT = wAll + 65536;
    float* b1af = bAll;
    float* b1bf = bAll + 128;
    float* b2af = bAll + 256;
    float* b2bf = bAll + 384;
    float* bfcf = bAll + 512;

    // ---- dtype detection + canonicalization
    k_detect<<<1, 256, 0, stream>>>((const unsigned int*)ei, (const unsigned int*)x, flags);
    k_cvt_feat<<<(NNODES * DF + 255) / 256, 256, 0, stream>>>(x, flags, B0, NNODES * DF);

    int wprepN = 4 * 16384 + NCP * 128 + 512 + NC;
    k_wprep<<<(wprepN + 255) / 256, 256, 0, stream>>>(w1a, w1b, w2a, w2b, wfc,
                                                      b1a, b1b, b2a, b2b, bfc,
                                                      flags, wAll, bAll);

    // ---- binned CSR build (reads edge_index directly)
    hipMemsetAsync(binCnt, 0, NB * 4, stream);
    int nEB = (NEDGES + CH - 1) / CH;                          // 391
    k_bincount<<<nEB, 256, 0, stream>>>(ei, flags, binCnt);
    k_binscan<<<1, 256, 0, stream>>>(binCnt, binOfs, binCur);
    k_binscatter<<<nEB, 256, 0, stream>>>(ei, flags, binCur, ebin);
    k_binfill<<<NB, 256, 0, stream>>>(ebin, binOfs, rowptr, perm);

    const int gatherGrid = NNODES / 4;                         // 25000

    // ---- layer 1
    k_gather<<<gatherGrid, 256, 0, stream>>>(B0, B0, rowptr, perm, B1);
    k_gemm_rb<<<GEMM_BLOCKS, 256, 0, stream>>>(B1, w1aT, b1af, B2);
    k_gemm_rb<<<GEMM_BLOCKS, 256, 0, stream>>>(B2, w1bT, b1bf, B1);   // h1 -> B1

    // ---- layer 2
    k_gather<<<gatherGrid, 256, 0, stream>>>(B1, B1, rowptr, perm, B2);
    k_gemm_rb<<<GEMM_BLOCKS, 256, 0, stream>>>(B2, w2aT, b2af, B0);
    k_gemm_rb<<<GEMM_BLOCKS, 256, 0, stream>>>(B0, w2bT, b2bf, B2);   // h2 -> B2

    // ---- fc + log_softmax
    k_fc_rb<<<GEMM_BLOCKS, 256, 0, stream>>>(B2, wfcT, bfcf, flags, d_out);
}